// Round 7
// baseline (791.829 us; speedup 1.0000x reference)
//
#include <hip/hip_runtime.h>
#include <hip/hip_bf16.h>

// Transposed conv (full conv): out[b,p,q,co] = sum_{kh,kw,ci} in[b,p-kh,q-kw,ci]*K[ci,co,kh,kw]
// B=8 H=W=256 C=64, out 8x258x258x64 fp32. bf16 MFMA path.
//
// R7 design (from R6 post-mortem; m233 lesson: 2-phase stage->barrier->compute
// overhead can't be removed piecemeal — restructure):
//  * Weights OUT of LDS, read from global (R5's coalesced fragment layout: each
//    wave-read = contiguous 1KB, L1/L2-hot) with explicit depth-1 register
//    double-buffer wb[2][4] so group g+1's load latency hides under group g's
//    8 MFMAs. Kills the 16x-redundant 1152 KB/tile LDS weight re-read (R1's
//    version of this path had NO prefetch -> exposed latency; that's fixed here).
//  * Freed LDS -> DOUBLE-BUFFERED patch (2x78336 = 153KB): commit(t+1)->bufB
//    runs in the MIDDLE of compute(t)->bufA, no intervening barrier. One
//    lgkmcnt(0)+s_barrier per tile. Loads for t+2 issued mid-compute; the
//    commit's load-deps are compiler-counted vmcnt (stores never drained).
// Patch XOR swizzle, fragment math, transposed-D epilogue, persistent 256-block
// grid: identical to verified R5/R6.

#define OH 258
#define OW 258

typedef __bf16 bf16x8 __attribute__((ext_vector_type(8)));
typedef float  f32x4  __attribute__((ext_vector_type(4)));

// ws layout (R5, verified): wsW[(((tap*2+s)*4+nt)*512) + h*128 + ml*8 + j]
//   = K[ci=32s+8h+j][co=16nt+ml][kh][kw],  tap=kh*3+kw
// => wave group (g=tap*2+s, nt) is a contiguous 1KB block; lane (ml,h) reads
//    bytes h*256+ml*16 .. +15 (perfectly coalesced).
__global__ void prep_w_kernel(const float* __restrict__ k, __bf16* __restrict__ wsW) {
    int i = blockIdx.x * 256 + threadIdx.x;            // [0, 36864)
    int j  = i & 7;
    int ml = (i >> 3) & 15;
    int h  = (i >> 7) & 3;
    int nt = (i >> 9) & 3;
    int st = i >> 11;                                  // [0,18)
    int s  = st & 1, tap = st >> 1;
    int ci = s * 32 + h * 8 + j;
    int co = nt * 16 + ml;
    wsW[i] = (__bf16)k[ci * 576 + co * 9 + tap];
}

__device__ __forceinline__ void tile_coords(int tau, int& b, int& p0, int& q0) {
    int bb = tau / 153;                                // 153 = 9 p-tiles * 17 q-tiles
    int rr = tau - bb * 153;
    int py = rr / 17;
    b  = bb;
    p0 = py * 32;
    q0 = (rr - py * 17) * 16;
}

// issue the 10 guarded global loads for one tile's 34x18 patch into regs
__device__ __forceinline__ void issue_patch_loads(
        const float* __restrict__ in, int b, int p0, int q0, int tid,
        f32x4 (&v0)[5], f32x4 (&v1)[5]) {
    #pragma unroll
    for (int k = 0; k < 5; ++k) {
        const int it = tid + k * 1024;                 // granule id, < 4896
        const bool act = (k < 4) || (tid < 800);
        int pix = it >> 3, c8 = it & 7;
        int r = pix / 18, c = pix - r * 18;
        int ip = p0 - 2 + r, iq = q0 - 2 + c;
        f32x4 z = {0.f, 0.f, 0.f, 0.f};
        v0[k] = z; v1[k] = z;
        if (act && (unsigned)ip < 256u && (unsigned)iq < 256u) {
            const float* g = in + (((size_t)b * 256 + ip) * 256 + iq) * 64 + c8 * 8;
            v0[k] = *(const f32x4*)g;
            v1[k] = *(const f32x4*)(g + 4);
        }
    }
}

// cvt staged regs -> bf16, swizzled ds_write into dst patch buffer
__device__ __forceinline__ void commit_patch(
        __bf16* __restrict__ dst, int tid,
        const f32x4 (&v0)[5], const f32x4 (&v1)[5]) {
    #pragma unroll
    for (int k = 0; k < 5; ++k) {
        const int it = tid + k * 1024;
        if ((k < 4) || (tid < 800)) {
            int pix = it >> 3, c8 = it & 7;
            bf16x8 w;
            w[0]=(__bf16)v0[k][0]; w[1]=(__bf16)v0[k][1];
            w[2]=(__bf16)v0[k][2]; w[3]=(__bf16)v0[k][3];
            w[4]=(__bf16)v1[k][0]; w[5]=(__bf16)v1[k][1];
            w[6]=(__bf16)v1[k][2]; w[7]=(__bf16)v1[k][3];
            *(bf16x8*)&dst[pix * 64 + ((c8 ^ (pix & 7)) * 8)] = w;
        }
    }
}

// groups g = tap*2+s in [G0,G1): weights from global with depth-1 reg prefetch,
// pixels from LDS patch. All indices compile-time after full unroll.
template<int G0, int G1>
__device__ __forceinline__ void compute_span(
        const __bf16* __restrict__ cur, const __bf16* __restrict__ wsW,
        int woff, int rbase, int ml, int h, f32x4 (&acc)[2][4]) {
    bf16x8 wb[2][4];
    #pragma unroll
    for (int nt = 0; nt < 4; ++nt)
        wb[G0 & 1][nt] = *(const bf16x8*)(wsW + G0 * 2048 + nt * 512 + woff);
    #pragma unroll
    for (int g = G0; g < G1; ++g) {
        if (g + 1 < G1) {                              // prefetch next group
            #pragma unroll
            for (int nt = 0; nt < 4; ++nt)
                wb[(g + 1) & 1][nt] =
                    *(const bf16x8*)(wsW + (g + 1) * 2048 + nt * 512 + woff);
        }
        const int tap = g >> 1, s = g & 1;
        const int kh = tap / 3, kw = tap - kh * 3;
        const int j = s * 4 + h;                       // 16B granule within pixel
        #pragma unroll
        for (int mt = 0; mt < 2; ++mt) {
            int row = rbase + mt + 2 - kh;             // patch row, in [0,34)
            int pix = row * 18 + (2 - kw) + ml;
            bf16x8 afr = *(const bf16x8*)&cur[pix * 64 + ((j ^ (pix & 7)) * 8)];
            #pragma unroll
            for (int nt = 0; nt < 4; ++nt)
                acc[mt][nt] = __builtin_amdgcn_mfma_f32_16x16x32_bf16(
                    wb[g & 1][nt], afr, acc[mt][nt], 0, 0, 0);
        }
    }
}

__global__ __launch_bounds__(1024, 4)
void tconv_kernel(const float* __restrict__ in, const __bf16* __restrict__ wsW,
                  float* __restrict__ out) {
    // two patch buffers [pix=34*18][64ci] bf16, XOR-swizzled granules
    __shared__ __bf16 lds_a[612 * 64];   // 78336 B
    __shared__ __bf16 lds_b[612 * 64];   // 78336 B ; 156672 total -> 1 block/CU

    const int tid = threadIdx.x;
    const int bx = blockIdx.x;
    const int n_t = (bx < 200) ? 5 : 4;    // 200*5 + 56*4 = 1224 tiles

    const int wv = tid >> 6, lane = tid & 63;
    const int ml = lane & 15, h = lane >> 4;
    const int woff = h * 128 + ml * 8;     // weight frag lane offset (coalesced)
    const int rbase = wv * 2;              // wave's 2 rows of the 32

    int cb, cp0, cq0;
    f32x4 v0[5], v1[5];

    // ---- prologue: tile 0 -> bufA; issue tile 1 loads
    tile_coords(bx, cb, cp0, cq0);
    issue_patch_loads(in, cb, cp0, cq0, tid, v0, v1);
    commit_patch(lds_a, tid, v0, v1);      // compiler-counted vmcnt before uses
    if (n_t > 1) {
        int nb, np0, nq0;
        tile_coords(bx + 256, nb, np0, nq0);
        issue_patch_loads(in, nb, np0, nq0, tid, v0, v1);
    }
    asm volatile("s_waitcnt lgkmcnt(0)" ::: "memory");
    __builtin_amdgcn_s_barrier();

    #pragma unroll 1
    for (int t = 0; t < n_t; ++t) {
        __bf16* cur = (t & 1) ? lds_b : lds_a;
        __bf16* nxt = (t & 1) ? lds_a : lds_b;
        tile_coords(bx + t * 256, cb, cp0, cq0);

        f32x4 acc[2][4] = {};   // mt = output row within wave's 2; nt = co/16

        compute_span<0, 9>(cur, wsW, woff, rbase, ml, h, acc);

        // ---- mid-compute: commit tile t+1 into the OTHER buffer (no barrier:
        // all waves finished READING nxt before the end-of-(t-1) barrier), then
        // issue tile t+2's loads to fly under the remaining compute.
        if (t + 1 < n_t) {
            commit_patch(nxt, tid, v0, v1);
            if (t + 2 < n_t) {
                int nb, np0, nq0;
                tile_coords(bx + (t + 2) * 256, nb, np0, nq0);
                issue_patch_loads(in, nb, np0, nq0, tid, v0, v1);
            }
        }

        compute_span<9, 18>(cur, wsW, woff, rbase, ml, h, acc);

        // ---- epilogue: D transposed; lane (ml,h) -> out[p][cq0+ml][nt*16+h*4..+3]
        // fire-and-forget stores, never drained in-loop
        const int q = cq0 + ml;
        #pragma unroll
        for (int mt = 0; mt < 2; ++mt) {
            int p = cp0 + rbase + mt;
            if (p < OH && q < OW) {
                float* op = out + (((size_t)cb * OH + p) * OW + q) * 64 + h * 4;
                #pragma unroll
                for (int nt = 0; nt < 4; ++nt)
                    *(f32x4*)(op + nt * 16) = acc[mt][nt];
            }
        }

        // ---- own ds ops drained, then barrier: commit(t+1) visible to all;
        // cur is free for iter t+1's commit of tile t+2. No vmcnt drain.
        asm volatile("s_waitcnt lgkmcnt(0)" ::: "memory");
        __builtin_amdgcn_s_barrier();
    }
}

extern "C" void kernel_launch(void* const* d_in, const int* in_sizes, int n_in,
                              void* d_out, int out_size, void* d_ws, size_t ws_size,
                              hipStream_t stream) {
    (void)in_sizes; (void)n_in; (void)out_size; (void)ws_size;
    const float* in   = (const float*)d_in[0];
    const float* kern = (const float*)d_in[1];
    float* out = (float*)d_out;
    __bf16* wsW = (__bf16*)d_ws;   // 36864 bf16 = 73728 B

    prep_w_kernel<<<144, 256, 0, stream>>>(kern, wsW);
    tconv_kernel<<<256, 1024, 0, stream>>>(in, wsW, out);
}